// Round 3
// baseline (389.525 us; speedup 1.0000x reference)
//
#include <hip/hip_runtime.h>
#include <hip/hip_bf16.h>
#include <math.h>

typedef unsigned short u16;
typedef __attribute__((ext_vector_type(8))) short bf16x8;
typedef __attribute__((ext_vector_type(4))) float f32x4;
typedef __attribute__((ext_vector_type(4))) unsigned int uint4v;
typedef __attribute__((ext_vector_type(2))) unsigned int uint2v;
typedef __attribute__((ext_vector_type(4))) unsigned short u16x4;

#define BB 2
#define LL 2048
#define KN 48
#define HH 128
#define NBLK (BB*LL)
#define ST 136   /* LDS stride for 48x128 tiles (68 dwords % 32 == 4) */

/* workspace layout in u16 units from (u16*)d_ws: [0..15]: flags */
#define WOFF      16
#define OFF_W1MT  (WOFF + 0)        /* [128][128]  W1 rows 128..255 ^T */
#define OFF_W1ST  (WOFF + 16384)    /* [128][128]  W1 rows 0..127  ^T */
#define OFF_W1GT  (WOFF + 32768)    /* [128][128]  W1 rows 256..383^T */
#define OFF_W2T   (WOFF + 49152)
#define OFF_W3T   (WOFF + 65536)
#define OFF_W11MT (WOFF + 81920)
#define OFF_W11ST (WOFF + 98304)
#define OFF_W11GT (WOFF + 114688)
#define OFF_W12T  (WOFF + 131072)
#define OFF_W13T  (WOFF + 147456)
#define OFF_WIT   (WOFF + 163840)   /* [512][128] */
#define OFF_WOT   (WOFF + 229376)   /* [128][512] */
#define OFF_HV1   (WOFF + 294912)   /* [B*L][128] LN1 output, bf16 */
#define OFF_Q1    (WOFF + 819200)   /* [B*L][128] bf16: hV0 @ W1[256:384] */
#define OFF_Q2    (WOFF + 1343488)  /* [B*L][128] bf16: hVnew @ W11[256:384] */
#define OFF_R1    (WOFF + 1867776)  /* [B*L][128] f32:  hV0 @ W1[0:128] + b1 */
#define OFF_R2    (WOFF + 2916352)  /* [B*L][128] f32:  hVnew @ W11[0:128] + b11 */
#define PREP_N    294912

__device__ __forceinline__ float b2f(u16 u){
    union { unsigned int i; float f; } v; v.i = ((unsigned int)u) << 16; return v.f;
}
__device__ __forceinline__ u16 f2b(float f){
    unsigned int x = __float_as_uint(f);
    unsigned int r = x + 0x7fffu + ((x >> 16) & 1u);
    return (u16)(r >> 16);
}
/* packed f32x2 -> bf16x2 (RNE), 1 VALU instr */
__device__ __forceinline__ unsigned int f2b2(float lo, float hi){
    unsigned int r;
    asm("v_cvt_pk_bf16_f32 %0, %1, %2" : "=v"(r) : "v"(lo), "v"(hi));
    return r;
}
/* fast GELU: exact-erf form via A&S 7.1.26 (|eps| <= 1.5e-7) */
__device__ __forceinline__ float gelu_f(float x){
    float ax = fabsf(x) * 0.70710678118654752f;          /* |x|/sqrt2 */
    float t  = __builtin_amdgcn_rcpf(fmaf(0.3275911f, ax, 1.0f));
    float e  = __builtin_amdgcn_exp2f(ax * ax * -1.4426950408889634f);
    float p  = fmaf(1.061405429f, t, -1.453152027f);
    p = fmaf(p, t, 1.421413741f);
    p = fmaf(p, t, -0.284496736f);
    p = fmaf(p, t, 0.254829592f);
    p = p * t;
    float erfv = fmaf(-p, e, 1.0f);                      /* erf(|x|/sqrt2) */
    float hx = 0.5f * x;
    return fmaf(fabsf(hx), erfv, hx);                    /* 0.5x + 0.5|x|erf */
}
__device__ __forceinline__ u16 ldb(const void* p, long i, int f32){
    return f32 ? f2b(((const float*)p)[i]) : ((const u16*)p)[i];
}
__device__ __forceinline__ float ldf(const void* p, long i, int f32){
    return f32 ? ((const float*)p)[i] : b2f(((const u16*)p)[i]);
}
/* 4 consecutive elements -> f32x4 (i must be multiple of 4) */
__device__ __forceinline__ f32x4 ldf4(const void* p, long i, int f32){
    f32x4 r;
    if (f32){
        r = *(const f32x4*)((const float*)p + i);
    } else {
        u16x4 v = *(const u16x4*)((const u16*)p + i);
        r[0]=b2f(v[0]); r[1]=b2f(v[1]); r[2]=b2f(v[2]); r[3]=b2f(v[3]);
    }
    return r;
}
__device__ __forceinline__ void st4(void* p, long i, f32x4 v, int f32){
    if (f32){
        *(f32x4*)((float*)p + i) = v;
    } else {
        uint2v u; u.x = f2b2(v[0], v[1]); u.y = f2b2(v[2], v[3]);
        *(uint2v*)((u16*)p + i) = u;
    }
}
__device__ __forceinline__ void stage8(u16* dst, const void* src, long off, int f32){
    if (f32){
        const float* s = (const float*)src + off;
        f32x4 a = *(const f32x4*)(s);
        f32x4 b = *(const f32x4*)(s + 4);
        uint4v v;
        v.x = f2b2(a[0], a[1]); v.y = f2b2(a[2], a[3]);
        v.z = f2b2(b[0], b[1]); v.w = f2b2(b[2], b[3]);
        *(uint4v*)dst = v;
    } else {
        *(uint4v*)dst = *(const uint4v*)((const u16*)src + off);
    }
}
__device__ __forceinline__ int ld_idx(const void* p, int i, int i64){
    int v = i64 ? ((const int*)p)[2*i] : ((const int*)p)[i];
    return v & (LL - 1);
}

/* ---- dtype detection ---- */
__global__ void detect_kernel(const void* ln1s, const void* maskV, const void* eidx, int* flags){
    if (threadIdx.x == 0){
        unsigned l0 = ((const unsigned*)ln1s)[0];
        unsigned m0 = ((const unsigned*)maskV)[0];
        int f32 = (l0 == 0x3F800000u || m0 == 0x3F800000u) ? 1 : 0;
        const int* e = (const int*)eidx;
        int orodd = 0, orlow = 0;
        for (int i = 1; i < 64; i += 2) orodd |= e[i];
        for (int i = 0; i < 64; i += 2) orlow |= e[i];
        flags[0] = f32;
        flags[1] = (orodd == 0 && orlow != 0) ? 1 : 0;
    }
}

/* ---- weight transpose prep ---- */
__global__ void prep_kernel(const void* W1, const void* W2, const void* W3,
                            const void* W11, const void* W12, const void* W13,
                            const void* Wi, const void* Wo, u16* wsbase){
    const int f32 = ((const int*)wsbase)[0];
    int i = blockIdx.x * 256 + threadIdx.x;
    if (i < 16384){ int n = i >> 7, k = i & 127; wsbase[OFF_W1MT + i] = ldb(W1, (128 + k)*128 + n, f32); }
    else if (i < 32768){ int j = i - 16384;  int n = j >> 7, k = j & 127; wsbase[OFF_W1ST  + j] = ldb(W1, k*128 + n, f32); }
    else if (i < 49152){ int j = i - 32768;  int n = j >> 7, k = j & 127; wsbase[OFF_W1GT  + j] = ldb(W1, (256 + k)*128 + n, f32); }
    else if (i < 65536){ int j = i - 49152;  int n = j >> 7, k = j & 127; wsbase[OFF_W2T   + j] = ldb(W2, k*128 + n, f32); }
    else if (i < 81920){ int j = i - 65536;  int n = j >> 7, k = j & 127; wsbase[OFF_W3T   + j] = ldb(W3, k*128 + n, f32); }
    else if (i < 98304){ int j = i - 81920;  int n = j >> 7, k = j & 127; wsbase[OFF_W11MT + j] = ldb(W11, (128 + k)*128 + n, f32); }
    else if (i < 114688){ int j = i - 98304; int n = j >> 7, k = j & 127; wsbase[OFF_W11ST + j] = ldb(W11, k*128 + n, f32); }
    else if (i < 131072){ int j = i - 114688;int n = j >> 7, k = j & 127; wsbase[OFF_W11GT + j] = ldb(W11, (256 + k)*128 + n, f32); }
    else if (i < 147456){ int j = i - 131072;int n = j >> 7, k = j & 127; wsbase[OFF_W12T  + j] = ldb(W12, k*128 + n, f32); }
    else if (i < 163840){ int j = i - 147456;int n = j >> 7, k = j & 127; wsbase[OFF_W13T  + j] = ldb(W13, k*128 + n, f32); }
    else if (i < 229376){ int j = i - 163840; int h = j >> 7, c = j & 127; wsbase[OFF_WIT + j] = ldb(Wi, c*512 + h, f32); }
    else if (i < 294912){ int j = i - 229376; int c = j >> 9, h = j & 511; wsbase[OFF_WOT + j] = ldb(Wo, h*128 + c, f32); }
}

/* ---- per-node precompute (pass 1): 8 nodes/block, 256 thr, 512 blocks.
   Q = h @ Wg (bf16), R = h @ Ws + bias (f32); lane owns node row r16 (<8) ---- */
__global__ __launch_bounds__(256, 8) void precomp_kernel(
    const void* __restrict__ src, const void* __restrict__ bias,
    u16* __restrict__ wsbase, long offWs, long offWg, long offQ, long offR)
{
    __shared__ alignas(16) u16 X[16 * ST];
    const int f32 = ((const int*)wsbase)[0];
    const int t = threadIdx.x, lane = t & 63, w = t >> 6;
    const int node0 = blockIdx.x * 8;
    const int r16 = lane & 15, q = lane >> 4, q8 = q * 8;

    {
        int row = t >> 4, ch = t & 15;
        if (t < 128){
            stage8(X + row * ST + ch * 8, src, ((long)(node0 + row)) * HH + ch * 8, f32);
        } else {
            uint4v z; z.x=0u; z.y=0u; z.z=0u; z.w=0u;
            *(uint4v*)(X + row * ST + ch * 8) = z;
        }
    }
    __syncthreads();

    const u16* bp = X + r16 * ST + q8;   /* B-frag: node row r16 */
#pragma unroll
    for (int half = 0; half < 2; half++){
        long offW = half ? offWg : offWs;
#pragma unroll
        for (int nt = 0; nt < 2; nt++){
            int wr = w * 32 + nt * 16 + r16;   /* weight row = output col (A-frag) */
            const u16* ap = wsbase + offW + (long)wr * 128 + q8;
            f32x4 acc; acc[0]=0.f; acc[1]=0.f; acc[2]=0.f; acc[3]=0.f;
#pragma unroll
            for (int kk = 0; kk < 4; kk++){
                bf16x8 av = *(const bf16x8*)(ap + kk * 32);
                bf16x8 bv = *(const bf16x8*)(bp + kk * 32);
                acc = __builtin_amdgcn_mfma_f32_16x16x32_bf16(av, bv, acc, 0, 0, 0);
            }
            int c0 = w * 32 + nt * 16 + q * 4;
            if (r16 < 8){
                if (half == 0){
                    f32x4 bc = ldf4(bias, c0, f32);
                    float* Rf = (float*)(wsbase + offR);
                    f32x4 rr; rr[0]=acc[0]+bc[0]; rr[1]=acc[1]+bc[1]; rr[2]=acc[2]+bc[2]; rr[3]=acc[3]+bc[3];
                    *(f32x4*)(Rf + (long)(node0 + r16) * HH + c0) = rr;
                } else {
                    uint2v u; u.x = f2b2(acc[0], acc[1]); u.y = f2b2(acc[2], acc[3]);
                    *(uint2v*)(wsbase + offQ + (long)(node0 + r16) * HH + c0) = u;
                }
            }
        }
    }
}

/* ---- swapped GEMM: D = W^T-tile (A) x message-rows (B); lane owns message
   row r16 (+16*mt) x 4 contiguous output cols (w*16 + q*4 ..) ---- */
__device__ __forceinline__ void mfma_WB(const u16* Mls, const bf16x8* W,
                                        f32x4 acc[3], int lane){
    const int r16 = lane & 15;
    const int q8  = (lane >> 4) * 8;
    const u16* bp = Mls + r16 * ST + q8;
#pragma unroll
    for (int kk = 0; kk < 4; kk++){
        bf16x8 b0 = *(const bf16x8*)(bp + kk * 32);
        bf16x8 b1 = *(const bf16x8*)(bp + 16 * ST + kk * 32);
        bf16x8 b2 = *(const bf16x8*)(bp + 32 * ST + kk * 32);
        acc[0] = __builtin_amdgcn_mfma_f32_16x16x32_bf16(W[kk], b0, acc[0], 0, 0, 0);
        acc[1] = __builtin_amdgcn_mfma_f32_16x16x32_bf16(W[kk], b1, acc[1], 0, 0, 0);
        acc[2] = __builtin_amdgcn_mfma_f32_16x16x32_bf16(W[kk], b2, acc[2], 0, 0, 0);
    }
}

__device__ __forceinline__ void zero_acc3(f32x4 acc[3]){
#pragma unroll
    for (int m = 0; m < 3; m++){ acc[m][0]=0.f; acc[m][1]=0.f; acc[m][2]=0.f; acc[m][3]=0.f; }
}

/* init acc with gathered-Q rows loaded directly from the L2-resident Q table
   (no LDS staging; issued before the staging barrier) */
__device__ __forceinline__ void init_accG(f32x4 acc[3], const u16* Qbase, const void* Eidx,
                                          int bid, int b, int i64, int lane, int w){
    const int r16 = lane & 15, q = lane >> 4;
    const int c0 = w * 16 + q * 4;
#pragma unroll
    for (int mt = 0; mt < 3; mt++){
        int nb = ld_idx(Eidx, bid * KN + mt * 16 + r16, i64);
        u16x4 v = *(const u16x4*)(Qbase + ((long)b * LL + nb) * HH + c0);
        acc[mt][0]=b2f(v[0]); acc[mt][1]=b2f(v[1]); acc[mt][2]=b2f(v[2]); acc[mt][3]=b2f(v[3]);
    }
}

/* +bias (per-col f32x4), optional gelu, pack, b64 LDS store */
__device__ __forceinline__ void store_T(f32x4 acc[3], u16* M, f32x4 bc4,
                                        int lane, int w, bool dogelu){
    const int r16 = lane & 15, q = lane >> 4;
    const int c0 = w * 16 + q * 4;
#pragma unroll
    for (int mt = 0; mt < 3; mt++){
        float v0 = acc[mt][0] + bc4[0], v1 = acc[mt][1] + bc4[1];
        float v2 = acc[mt][2] + bc4[2], v3 = acc[mt][3] + bc4[3];
        if (dogelu){ v0 = gelu_f(v0); v1 = gelu_f(v1); v2 = gelu_f(v2); v3 = gelu_f(v3); }
        uint2v u; u.x = f2b2(v0, v1); u.y = f2b2(v2, v3);
        *(uint2v*)(M + (mt * 16 + r16) * ST + c0) = u;
    }
}

/* ---- kernel 1: node message + LN1 -> hv1 (ws) ---- */
__global__ __launch_bounds__(512, 6) void node_kernel(
    const void* __restrict__ hV, const void* __restrict__ hE, const void* __restrict__ Eidx,
    const void* __restrict__ maskA,
    const void* __restrict__ b2, const void* __restrict__ b3,
    const void* __restrict__ ln1s, const void* __restrict__ ln1b,
    u16* __restrict__ wsbase)
{
    __shared__ alignas(16) u16 A[KN * ST];    /* h_E bf16; M2 aliases */
    __shared__ alignas(16) u16 M1[KN * ST];
    __shared__ float smask[KN];
    __shared__ alignas(16) float dh[HH];
    __shared__ float hv0f[HH];
    u16* M2 = A;

    const int f32 = ((const int*)wsbase)[0];
    const int i64 = ((const int*)wsbase)[1];
    const u16* ws = wsbase;
    const int t = threadIdx.x, lane = t & 63, w = t >> 6;
    const int bid = blockIdx.x;
    const int b = bid >> 11;
    const int r16 = lane & 15, q = lane >> 4, q8 = q * 8;
    const int wrow = w * 16 + r16;   /* weight row (A-frag lane index) */
    const int c0 = w * 16 + q * 4;   /* this lane's 4 output cols */

    /* gathered-Q acc init: direct L2 loads, issued before any barrier */
    f32x4 acc[3];
    init_accG(acc, ws + OFF_Q1, Eidx, bid, b, i64, lane, w);

    /* prefetch W1-mid fragments (A-operand) */
    bf16x8 B1[4];
    {
        const u16* bp = ws + OFF_W1MT + (long)wrow * 128 + q8;
#pragma unroll
        for (int k = 0; k < 4; k++) B1[k] = *(const bf16x8*)(bp + k * 32);
    }

    for (int i = t; i < 768; i += 512){
        int row = i >> 4, ch = i & 15;
        stage8(A + row * ST + ch * 8, hE, ((long)bid * KN + row) * HH + ch * 8, f32);
    }
    if (t < HH) hv0f[t] = ldf(hV, (long)bid * HH + t, f32);
    if (t < KN) smask[t] = ldf(maskA, bid * KN + t, f32);

    bf16x8 B2[4];
    {
        const u16* bp = ws + OFF_W2T + (long)wrow * 128 + q8;
#pragma unroll
        for (int k = 0; k < 4; k++) B2[k] = *(const bf16x8*)(bp + k * 32);
    }
    /* per-col effective bias: b1 + hV_self @ W1[0:128] (precomputed f32) */
    const f32x4 bc1 = *(const f32x4*)((const float*)(wsbase + OFF_R1) + (long)bid * HH + c0);
    __syncthreads();

    __builtin_amdgcn_s_setprio(1);
    mfma_WB(A, B1, acc, lane);
    __builtin_amdgcn_s_setprio(0);
    store_T(acc, M1, bc1, lane, w, true);

    bf16x8 B3[4];
    {
        const u16* bp = ws + OFF_W3T + (long)wrow * 128 + q8;
#pragma unroll
        for (int k = 0; k < 4; k++) B3[k] = *(const bf16x8*)(bp + k * 32);
    }
    __syncthreads();

    zero_acc3(acc);
    __builtin_amdgcn_s_setprio(1);
    mfma_WB(M1, B2, acc, lane);
    __builtin_amdgcn_s_setprio(0);
    store_T(acc, M2, ldf4(b2, c0, f32), lane, w, true);
    __syncthreads();

    zero_acc3(acc);
    __builtin_amdgcn_s_setprio(1);
    mfma_WB(M2, B3, acc, lane);
    __builtin_amdgcn_s_setprio(0);

    /* masked k-reduction -> dh: lane has rows {r16,16+r16,32+r16} x cols c0.. */
    {
        f32x4 b3v = ldf4(b3, c0, f32);
        f32x4 s; s[0]=0.f; s[1]=0.f; s[2]=0.f; s[3]=0.f;
#pragma unroll
        for (int mt = 0; mt < 3; mt++){
            float mk = smask[mt * 16 + r16];
#pragma unroll
            for (int j = 0; j < 4; j++) s[j] += mk * (acc[mt][j] + b3v[j]);
        }
#pragma unroll
        for (int off = 1; off <= 8; off <<= 1){
#pragma unroll
            for (int j = 0; j < 4; j++) s[j] += __shfl_xor(s[j], off);
        }
        if (r16 == 0) *(f32x4*)&dh[c0] = s;
    }
    __syncthreads();

    /* LN1 (wave 0) -> hv1 bf16 */
    if (w == 0){
        float xa = hv0f[lane]      + dh[lane]      * (1.0f / 30.0f);
        float xb = hv0f[64 + lane] + dh[64 + lane] * (1.0f / 30.0f);
        float sum = xa + xb, sq = xa * xa + xb * xb;
#pragma unroll
        for (int off = 1; off < 64; off <<= 1){ sum += __shfl_xor(sum, off); sq += __shfl_xor(sq, off); }
        float mu = sum * (1.0f / 128.0f);
        float var = sq * (1.0f / 128.0f) - mu * mu;
        float rstd = rsqrtf(var + 1e-5f);
        wsbase[OFF_HV1 + (long)bid * HH + lane] =
            f2b((xa - mu) * rstd * ldf(ln1s, lane, f32) + ldf(ln1b, lane, f32));
        wsbase[OFF_HV1 + (long)bid * HH + 64 + lane] =
            f2b((xb - mu) * rstd * ldf(ln1s, 64 + lane, f32) + ldf(ln1b, 64 + lane, f32));
    }
}

/* ---- kernel 2: FFN, 8 nodes/block, 256 thr, 512 blocks. LN2 + mask -> d_out;
   fused precomp pass 2 (Q2/R2 for the edge kernel) ---- */
__global__ __launch_bounds__(256, 8) void ffn_kernel(
    const void* __restrict__ maskV,
    const void* __restrict__ bi, const void* __restrict__ bo,
    const void* __restrict__ b11,
    const void* __restrict__ ln2s, const void* __restrict__ ln2b,
    u16* __restrict__ wsbase, void* __restrict__ dout)
{
    __shared__ alignas(16) u16 X[16 * 136];
    __shared__ alignas(16) u16 Hid[16 * 520];
    __shared__ alignas(16) float V[16 * 132];

    const int f32 = ((const int*)wsbase)[0];
    const u16* ws = wsbase;
    const u16* hv1 = wsbase + OFF_HV1;
    const int t = threadIdx.x, lane = t & 63, w = t >> 6;   /* w in 0..3 */
    const int node0 = blockIdx.x * 8;
    const int r16 = lane & 15, q = lane >> 4, q8 = q * 8;

    {
        int row = t >> 4, ch = t & 15;
        if (t < 128){
            *(uint4v*)(X + row * 136 + ch * 8) =
                *(const uint4v*)(hv1 + (long)(node0 + row) * HH + ch * 8);
        } else {
            uint4v z; z.x=0u; z.y=0u; z.z=0u; z.w=0u;
            *(uint4v*)(X + row * 136 + ch * 8) = z;
        }
    }
    __syncthreads();

    /* GEMM1 swapped: A = WiT rows (8 tiles: w*128 + nt*16), B = X rows */
    f32x4 acc[8];
#pragma unroll
    for (int nt = 0; nt < 8; nt++){ acc[nt][0]=0.f; acc[nt][1]=0.f; acc[nt][2]=0.f; acc[nt][3]=0.f; }
    {
        const u16* bp = X + r16 * 136 + q8;
#pragma unroll
        for (int kk = 0; kk < 4; kk++){
            bf16x8 bv = *(const bf16x8*)(bp + kk * 32);
#pragma unroll
            for (int nt = 0; nt < 8; nt++){
                const u16* ap = ws + OFF_WIT + (long)(w * 128 + nt * 16 + r16) * 128 + kk * 32 + q8;
                bf16x8 av = *(const bf16x8*)ap;
                acc[nt] = __builtin_amdgcn_mfma_f32_16x16x32_bf16(av, bv, acc[nt], 0, 0, 0);
            }
        }
    }
    /* lane owns node row r16 (<8 valid) x 4 contiguous hid cols */
#pragma unroll
    for (int nt = 0; nt < 8; nt++){
        int hc0 = w * 128 + nt * 16 + q * 4;
        f32x4 bc = ldf4(bi, hc0, f32);
        float g0 = gelu_f(acc[nt][0] + bc[0]), g1 = gelu_f(acc[nt][1] + bc[1]);
        float g2 = gelu_f(acc[nt][2] + bc[2]), g3 = gelu_f(acc[nt][3] + bc[3]);
        uint2v u; u.x = f2b2(g0, g1); u.y = f2b2(g2, g3);
        *(uint2v*)(Hid + r16 * 520 + hc0) = u;
    }
    __syncthreads();

    /* GEMM2 swapped: A = WoT rows (w*32 + nt*16 + r16), B = Hid rows; K=512 */
    f32x4 acc2[2];
#pragma unroll
    for (int nt = 0; nt < 2; nt++){ acc2[nt][0]=0.f; acc2[nt][1]=0.f; acc2[nt][2]=0.f; acc2[nt][3]=0.f; }
    {
        const u16* bp2 = Hid + r16 * 520 + q8;
        __builtin_amdgcn_s_setprio(1);
#pragma unroll
        for (int kk = 0; kk < 16; kk++){
            bf16x8 bv = *(const bf16x8*)(bp2 + kk * 32);
#pragma unroll
            for (int nt = 0; nt < 2; nt++){
                const u16* ap = ws + OFF_WOT + (long)(w * 32 + nt * 16 + r16) * 512 + kk * 32 + q8;
                bf16x8 av = *(const bf16x8*)ap;
                acc2[nt] = __builtin_amdgcn_mfma_f32_16x16x32_bf16(av, bv, acc2[nt], 0, 0, 0);
            }
        }
        __builtin_amdgcn_s_setprio(0);
    }
    {   /* V = acc2 + bo + residual; lane: node row r16, cols cc0.. */
#pragma unroll
        for (int nt = 0; nt < 2; nt++){
            int cc0 = w * 32 + nt * 16 + q * 4;
            f32x4 bo4 = ldf4(bo, cc0, f32);
            u16x4 xr = *(const u16x4*)(X + r16 * 136 + cc0);
            f32x4 vv;
            vv[0] = acc2[nt][0] + bo4[0] + b2f(xr[0]);
            vv[1] = acc2[nt][1] + bo4[1] + b2f(xr[1]);
            vv[2] = acc2[nt][2] + bo4[2] + b2f(xr[2]);
            vv[3] = acc2[nt][3] + bo4[3] + b2f(xr[3]);
            *(f32x4*)&V[r16 * 132 + cc0] = vv;
        }
    }
    __syncthreads();

    /* LN2 + mask: 32 threads per row (rows 0..7); store d_out and bf16 copy into X */
    {
        int row = t >> 5, p = t & 31;
        f32x4 v = *(const f32x4*)&V[row * 132 + p * 4];
        float sum = v[0] + v[1] + v[2] + v[3];
        float sq = v[0]*v[0] + v[1]*v[1] + v[2]*v[2] + v[3]*v[3];
#pragma unroll
        for (int off = 1; off < 32; off <<= 1){ sum += __shfl_xor(sum, off); sq += __shfl_xor(sq, off); }
        float mu = sum * (1.0f / 128.0f);
        float var = sq * (1.0f / 128.0f) - mu * mu;
        float rstd = rsqrtf(var + 1e-5f);
        float mv = ldf(maskV, node0 + row, f32);
        f32x4 s4 = ldf4(ln2s, p * 4, f32), bb4 = ldf4(ln2b, p * 4, f32);
        f32x4 y;
#pragma unroll
        for (int j = 0; j < 4; j++) y[j] = ((v[j] - mu) * rstd * s4[j] + bb4[j]) * mv;
        st4(dout, (long)(node0 + row) * HH + p * 4, y, f32);
        uint2v u; u.x = f2b2(y[0], y[1]); u.y = f2b2(y[2], y[3]);
        *(uint2v*)(X + row * 136 + p * 4) = u;
    }
    __syncthreads();

    /* fused precomp2: R2 = hv_new @ W11[0:128] + b11 (f32), Q2 = hv_new @ W11[256:384] (bf16) */
    {
        const u16* bp = X + r16 * 136 + q8;
#pragma unroll
        for (int nt = 0; nt < 2; nt++){
            int wr = w * 32 + nt * 16 + r16;
            f32x4 aR, aQ;
            aR[0]=0.f; aR[1]=0.f; aR[2]=0.f; aR[3]=0.f;
            aQ[0]=0.f; aQ[1]=0.f; aQ[2]=0.f; aQ[3]=0.f;
#pragma unroll
            for (int kk = 0; kk < 4; kk++){
                bf16x8 bv = *(const bf16x8*)(bp + kk * 32);
                bf16x8 avR = *(const bf16x8*)(ws + OFF_W11ST + (long)wr * 128 + kk * 32 + q8);
                bf16x8 avQ = *(const bf16x8*)(ws + OFF_W11GT + (long)wr * 128 + kk * 32 + q8);
                aR = __builtin_amdgcn_mfma_f32_16x16x32_bf16(avR, bv, aR, 0, 0, 0);
                aQ = __builtin_amdgcn_mfma_f32_16x16x32_bf16(avQ, bv, aQ, 0, 0, 0);
            }
            if (r16 < 8){
                int cc0 = w * 32 + nt * 16 + q * 4;
                f32x4 b11v = ldf4(b11, cc0, f32);
                float* Rf = (float*)(wsbase + OFF_R2);
                f32x4 rr;
#pragma unroll
                for (int j = 0; j < 4; j++) rr[j] = aR[j] + b11v[j];
                *(f32x4*)(Rf + (long)(node0 + r16) * HH + cc0) = rr;
                uint2v u; u.x = f2b2(aQ[0], aQ[1]); u.y = f2b2(aQ[2], aQ[3]);
                *(uint2v*)(wsbase + OFF_Q2 + (long)(node0 + r16) * HH + cc0) = u;
            }
        }
    }
}

/* ---- kernel 3: edge update + LN3 (gathers precomputed Q2 from ws) ---- */
__global__ __launch_bounds__(512, 6) void edge_kernel(
    const void* __restrict__ hE, const void* __restrict__ Eidx,
    const void* __restrict__ b12, const void* __restrict__ b13,
    const void* __restrict__ ln3s, const void* __restrict__ ln3b,
    u16* __restrict__ wsbase, void* __restrict__ dout)
{
    __shared__ alignas(16) u16 A[KN * ST];    /* h_E bf16; M2 aliases */
    __shared__ alignas(16) u16 M1[KN * ST];
    __shared__ float rowsum[KN];
    __shared__ float rowsq[KN];
    u16* M2 = A;

    const int f32 = ((const int*)wsbase)[0];
    const int i64 = ((const int*)wsbase)[1];
    const u16* ws = wsbase;
    const int t = threadIdx.x, lane = t & 63, w = t >> 6;
    const int bid = blockIdx.x;
    const int b = bid >> 11;
    const int r16 = lane & 15, q = lane >> 4, q8 = q * 8;
    const int wrow = w * 16 + r16;
    const int c0 = w * 16 + q * 4;

    /* gathered-Q2 acc init: direct L2 loads, issued before any barrier */
    f32x4 acc[3];
    init_accG(acc, ws + OFF_Q2, Eidx, bid, b, i64, lane, w);

    bf16x8 B1[4];
    {
        const u16* bp = ws + OFF_W11MT + (long)wrow * 128 + q8;
#pragma unroll
        for (int k = 0; k < 4; k++) B1[k] = *(const bf16x8*)(bp + k * 32);
    }

    for (int i = t; i < 768; i += 512){
        int row = i >> 4, ch = i & 15;
        stage8(A + row * ST + ch * 8, hE, ((long)bid * KN + row) * HH + ch * 8, f32);
    }
    if (t < KN){ rowsum[t] = 0.f; rowsq[t] = 0.f; }

    bf16x8 B2[4];
    {
        const u16* bp = ws + OFF_W12T + (long)wrow * 128 + q8;
#pragma unroll
        for (int k = 0; k < 4; k++) B2[k] = *(const bf16x8*)(bp + k * 32);
    }
    const f32x4 bc1 = *(const f32x4*)((const float*)(wsbase + OFF_R2) + (long)bid * HH + c0);
    __syncthreads();

    __builtin_amdgcn_s_setprio(1);
    mfma_WB(A, B1, acc, lane);
    __builtin_amdgcn_s_setprio(0);
    store_T(acc, M1, bc1, lane, w, true);

    bf16x8 B3[4];
    {
        const u16* bp = ws + OFF_W13T + (long)wrow * 128 + q8;
#pragma unroll
        for (int k = 0; k < 4; k++) B3[k] = *(const bf16x8*)(bp + k * 32);
    }
    __syncthreads();

    zero_acc3(acc);
    __builtin_amdgcn_s_setprio(1);
    mfma_WB(M1, B2, acc, lane);
    __builtin_amdgcn_s_setprio(0);
    store_T(acc, M2, ldf4(b12, c0, f32), lane, w, true);
    __syncthreads();

    zero_acc3(acc);
    __builtin_amdgcn_s_setprio(1);
    mfma_WB(M2, B3, acc, lane);
    __builtin_amdgcn_s_setprio(0);

    /* epilogue: lane owns rows {r16, 16+r16, 32+r16} x cols c0..c0+3 */
    f32x4 vals[3];
    {
        f32x4 b13v = ldf4(b13, c0, f32);
#pragma unroll
        for (int mt = 0; mt < 3; mt++){
            int r = mt * 16 + r16;
            f32x4 res = ldf4(hE, ((long)bid * KN + r) * HH + c0, f32);  /* residual (L2-hit) */
#pragma unroll
            for (int j = 0; j < 4; j++) vals[mt][j] = acc[mt][j] + b13v[j] + res[j];
        }
    }
    /* LN3 stats: per-lane 4-col partials, reduce over q (xor 16,32), cross-wave atomics */
    {
        float s[3], ss[3];
#pragma unroll
        for (int mt = 0; mt < 3; mt++){
            s[mt]  = vals[mt][0] + vals[mt][1] + vals[mt][2] + vals[mt][3];
            ss[mt] = vals[mt][0]*vals[mt][0] + vals[mt][1]*vals[mt][1]
                   + vals[mt][2]*vals[mt][2] + vals[mt][3]*vals[mt][3];
            s[mt]  += __shfl_xor(s[mt], 16);  s[mt]  += __shfl_xor(s[mt], 32);
            ss[mt] += __shfl_xor(ss[mt], 16); ss[mt] += __shfl_xor(ss[mt], 32);
        }
        if (lane < 16){
#pragma unroll
            for (int mt = 0; mt < 3; mt++){
                atomicAdd(&rowsum[mt * 16 + lane], s[mt]);
                atomicAdd(&rowsq[mt * 16 + lane], ss[mt]);
            }
        }
    }
    __syncthreads();
    if (t < KN){
        float mu = rowsum[t] * (1.0f / 128.0f);
        float var = rowsq[t] * (1.0f / 128.0f) - mu * mu;
        rowsum[t] = mu;
        rowsq[t] = rsqrtf(var + 1e-5f);
    }
    __syncthreads();

    {
        long ebase = (long)BB * LL * HH;
        f32x4 g4 = ldf4(ln3s, c0, f32), be4 = ldf4(ln3b, c0, f32);
#pragma unroll
        for (int mt = 0; mt < 3; mt++){
            int r = mt * 16 + r16;
            float mu = rowsum[r], rs = rowsq[r];
            f32x4 y;
#pragma unroll
            for (int j = 0; j < 4; j++) y[j] = (vals[mt][j] - mu) * rs * g4[j] + be4[j];
            st4(dout, ebase + ((long)bid * KN + r) * HH + c0, y, f32);
        }
    }
}

extern "C" void kernel_launch(void* const* d_in, const int* in_sizes, int n_in,
                              void* d_out, int out_size, void* d_ws, size_t ws_size,
                              hipStream_t stream) {
    const void* hV    = d_in[0];
    const void* hE    = d_in[1];
    const void* Eidx  = d_in[2];
    const void* maskV = d_in[3];
    const void* maskA = d_in[4];
    const void* W1  = d_in[5];  const void* b1  = d_in[6];
    const void* W2  = d_in[7];  const void* b2  = d_in[8];
    const void* W3  = d_in[9];  const void* b3  = d_in[10];
    const void* W11 = d_in[11]; const void* b11 = d_in[12];
    const void* W12 = d_in[13]; const void* b12 = d_in[14];
    const void* W13 = d_in[15]; const void* b13 = d_in[16];
    const void* Wi  = d_in[17]; const void* bi  = d_in[18];
    const void* Wo  = d_in[19]; const void* bo  = d_in[20];
    const void* ln1s = d_in[21]; const void* ln1b = d_in[22];
    const void* ln2s = d_in[23]; const void* ln2b = d_in[24];
    const void* ln3s = d_in[25]; const void* ln3b = d_in[26];

    u16* ws = (u16*)d_ws;

    detect_kernel<<<1, 64, 0, stream>>>(ln1s, maskV, Eidx, (int*)d_ws);
    prep_kernel<<<(PREP_N + 255) / 256, 256, 0, stream>>>(W1, W2, W3, W11, W12, W13, Wi, Wo, ws);
    precomp_kernel<<<NBLK / 8, 256, 0, stream>>>(hV, b1, ws,
                                                 (long)OFF_W1ST, (long)OFF_W1GT,
                                                 (long)OFF_Q1, (long)OFF_R1);
    node_kernel<<<NBLK, 512, 0, stream>>>(hV, hE, Eidx, maskA,
                                          b2, b3, ln1s, ln1b, ws);
    ffn_kernel<<<NBLK / 8, 256, 0, stream>>>(maskV, bi, bo, b11, ln2s, ln2b, ws, d_out);
    edge_kernel<<<NBLK, 512, 0, stream>>>(hE, Eidx, b12, b13,
                                          ln3s, ln3b, ws, d_out);
}

// Round 4
// 370.328 us; speedup vs baseline: 1.0518x; 1.0518x over previous
//
#include <hip/hip_runtime.h>
#include <hip/hip_bf16.h>
#include <math.h>

typedef unsigned short u16;
typedef __attribute__((ext_vector_type(8))) short bf16x8;
typedef __attribute__((ext_vector_type(4))) float f32x4;
typedef __attribute__((ext_vector_type(4))) unsigned int uint4v;
typedef __attribute__((ext_vector_type(2))) unsigned int uint2v;
typedef __attribute__((ext_vector_type(4))) unsigned short u16x4;

#define BB 2
#define LL 2048
#define KN 48
#define HH 128
#define NBLK (BB*LL)
#define ST 136   /* LDS stride for 48x128 tiles (68 dwords % 32 == 4) */

/* workspace layout in u16 units from (u16*)d_ws: [0..15]: flags */
#define WOFF      16
#define OFF_W1MT  (WOFF + 0)        /* [128][128]  W1 rows 128..255 ^T */
#define OFF_W1ST  (WOFF + 16384)    /* [128][128]  W1 rows 0..127  ^T */
#define OFF_W1GT  (WOFF + 32768)    /* [128][128]  W1 rows 256..383^T */
#define OFF_W2T   (WOFF + 49152)
#define OFF_W3T   (WOFF + 65536)
#define OFF_W11MT (WOFF + 81920)
#define OFF_W11ST (WOFF + 98304)
#define OFF_W11GT (WOFF + 114688)
#define OFF_W12T  (WOFF + 131072)
#define OFF_W13T  (WOFF + 147456)
#define OFF_WIT   (WOFF + 163840)   /* [512][128] */
#define OFF_WOT   (WOFF + 229376)   /* [128][512] */
#define OFF_HV1   (WOFF + 294912)   /* [B*L][128] LN1 output, bf16 */
#define OFF_Q1    (WOFF + 819200)   /* [B*L][128] bf16: hV0 @ W1[256:384] */
#define OFF_Q2    (WOFF + 1343488)  /* [B*L][128] bf16: hVnew @ W11[256:384] */
#define OFF_R1    (WOFF + 1867776)  /* [B*L][128] f32:  hV0 @ W1[0:128] + b1 */
#define OFF_R2    (WOFF + 2916352)  /* [B*L][128] f32:  hVnew @ W11[0:128] + b11 */
#define PREP_N    294912

__device__ __forceinline__ float b2f(u16 u){
    union { unsigned int i; float f; } v; v.i = ((unsigned int)u) << 16; return v.f;
}
__device__ __forceinline__ u16 f2b(float f){
    unsigned int x = __float_as_uint(f);
    unsigned int r = x + 0x7fffu + ((x >> 16) & 1u);
    return (u16)(r >> 16);
}
/* packed f32x2 -> bf16x2 (RNE), 1 VALU instr */
__device__ __forceinline__ unsigned int f2b2(float lo, float hi){
    unsigned int r;
    asm("v_cvt_pk_bf16_f32 %0, %1, %2" : "=v"(r) : "v"(lo), "v"(hi));
    return r;
}
/* fast GELU: exact-erf form via A&S 7.1.26 (|eps| <= 1.5e-7) */
__device__ __forceinline__ float gelu_f(float x){
    float ax = fabsf(x) * 0.70710678118654752f;          /* |x|/sqrt2 */
    float t  = __builtin_amdgcn_rcpf(fmaf(0.3275911f, ax, 1.0f));
    float e  = __builtin_amdgcn_exp2f(ax * ax * -1.4426950408889634f);
    float p  = fmaf(1.061405429f, t, -1.453152027f);
    p = fmaf(p, t, 1.421413741f);
    p = fmaf(p, t, -0.284496736f);
    p = fmaf(p, t, 0.254829592f);
    p = p * t;
    float erfv = fmaf(-p, e, 1.0f);                      /* erf(|x|/sqrt2) */
    float hx = 0.5f * x;
    return fmaf(fabsf(hx), erfv, hx);                    /* 0.5x + 0.5|x|erf */
}
__device__ __forceinline__ u16 ldb(const void* p, long i, int f32){
    return f32 ? f2b(((const float*)p)[i]) : ((const u16*)p)[i];
}
__device__ __forceinline__ float ldf(const void* p, long i, int f32){
    return f32 ? ((const float*)p)[i] : b2f(((const u16*)p)[i]);
}
/* 4 consecutive elements -> f32x4 (i must be multiple of 4) */
__device__ __forceinline__ f32x4 ldf4(const void* p, long i, int f32){
    f32x4 r;
    if (f32){
        r = *(const f32x4*)((const float*)p + i);
    } else {
        u16x4 v = *(const u16x4*)((const u16*)p + i);
        r[0]=b2f(v[0]); r[1]=b2f(v[1]); r[2]=b2f(v[2]); r[3]=b2f(v[3]);
    }
    return r;
}
__device__ __forceinline__ void st4(void* p, long i, f32x4 v, int f32){
    if (f32){
        *(f32x4*)((float*)p + i) = v;
    } else {
        uint2v u; u.x = f2b2(v[0], v[1]); u.y = f2b2(v[2], v[3]);
        *(uint2v*)((u16*)p + i) = u;
    }
}
__device__ __forceinline__ void stage8(u16* dst, const void* src, long off, int f32){
    if (f32){
        const float* s = (const float*)src + off;
        f32x4 a = *(const f32x4*)(s);
        f32x4 b = *(const f32x4*)(s + 4);
        uint4v v;
        v.x = f2b2(a[0], a[1]); v.y = f2b2(a[2], a[3]);
        v.z = f2b2(b[0], b[1]); v.w = f2b2(b[2], b[3]);
        *(uint4v*)dst = v;
    } else {
        *(uint4v*)dst = *(const uint4v*)((const u16*)src + off);
    }
}
__device__ __forceinline__ int ld_idx(const void* p, int i, int i64){
    int v = i64 ? ((const int*)p)[2*i] : ((const int*)p)[i];
    return v & (LL - 1);
}

/* ---- weight transpose prep; block 0 also publishes the dtype flags ---- */
__global__ void prep_kernel(const void* W1, const void* W2, const void* W3,
                            const void* W11, const void* W12, const void* W13,
                            const void* Wi, const void* Wo,
                            const void* ln1s, const void* maskV, const void* eidx,
                            u16* wsbase){
    /* self-detect f32 (flags in ws are not yet valid) */
    unsigned l0 = ((const unsigned*)ln1s)[0];
    unsigned m0 = ((const unsigned*)maskV)[0];
    const int f32 = (l0 == 0x3F800000u || m0 == 0x3F800000u) ? 1 : 0;
    if (blockIdx.x == 0 && threadIdx.x == 0){
        const int* e = (const int*)eidx;
        int orodd = 0, orlow = 0;
        for (int i = 1; i < 64; i += 2) orodd |= e[i];
        for (int i = 0; i < 64; i += 2) orlow |= e[i];
        ((int*)wsbase)[0] = f32;
        ((int*)wsbase)[1] = (orodd == 0 && orlow != 0) ? 1 : 0;
    }
    int i = blockIdx.x * 256 + threadIdx.x;
    if (i < 16384){ int n = i >> 7, k = i & 127; wsbase[OFF_W1MT + i] = ldb(W1, (128 + k)*128 + n, f32); }
    else if (i < 32768){ int j = i - 16384;  int n = j >> 7, k = j & 127; wsbase[OFF_W1ST  + j] = ldb(W1, k*128 + n, f32); }
    else if (i < 49152){ int j = i - 32768;  int n = j >> 7, k = j & 127; wsbase[OFF_W1GT  + j] = ldb(W1, (256 + k)*128 + n, f32); }
    else if (i < 65536){ int j = i - 49152;  int n = j >> 7, k = j & 127; wsbase[OFF_W2T   + j] = ldb(W2, k*128 + n, f32); }
    else if (i < 81920){ int j = i - 65536;  int n = j >> 7, k = j & 127; wsbase[OFF_W3T   + j] = ldb(W3, k*128 + n, f32); }
    else if (i < 98304){ int j = i - 81920;  int n = j >> 7, k = j & 127; wsbase[OFF_W11MT + j] = ldb(W11, (128 + k)*128 + n, f32); }
    else if (i < 114688){ int j = i - 98304; int n = j >> 7, k = j & 127; wsbase[OFF_W11ST + j] = ldb(W11, k*128 + n, f32); }
    else if (i < 131072){ int j = i - 114688;int n = j >> 7, k = j & 127; wsbase[OFF_W11GT + j] = ldb(W11, (256 + k)*128 + n, f32); }
    else if (i < 147456){ int j = i - 131072;int n = j >> 7, k = j & 127; wsbase[OFF_W12T  + j] = ldb(W12, k*128 + n, f32); }
    else if (i < 163840){ int j = i - 147456;int n = j >> 7, k = j & 127; wsbase[OFF_W13T  + j] = ldb(W13, k*128 + n, f32); }
    else if (i < 229376){ int j = i - 163840; int h = j >> 7, c = j & 127; wsbase[OFF_WIT + j] = ldb(Wi, c*512 + h, f32); }
    else if (i < 294912){ int j = i - 229376; int c = j >> 9, h = j & 511; wsbase[OFF_WOT + j] = ldb(Wo, h*128 + c, f32); }
}

/* ---- per-node precompute (pass 1): 16 nodes/block, 256 thr.
   Q = h @ Wg (bf16), R = h @ Ws + bias (f32); lane owns node row r16 x 4 cols ---- */
__global__ __launch_bounds__(256) void precomp_kernel(
    const void* __restrict__ src, const void* __restrict__ bias,
    u16* __restrict__ wsbase, long offWs, long offWg, long offQ, long offR)
{
    __shared__ alignas(16) u16 X[16 * ST];
    const int f32 = ((const int*)wsbase)[0];
    const int t = threadIdx.x, lane = t & 63, w = t >> 6;
    const int node0 = blockIdx.x * 16;
    const int r16 = lane & 15, q = lane >> 4, q8 = q * 8;

    {
        int row = t >> 4, ch = t & 15;
        stage8(X + row * ST + ch * 8, src, ((long)(node0 + row)) * HH + ch * 8, f32);
    }
    __syncthreads();

    const u16* bp = X + r16 * ST + q8;   /* B-frag: node row r16 */
#pragma unroll
    for (int half = 0; half < 2; half++){
        long offW = half ? offWg : offWs;
#pragma unroll
        for (int nt = 0; nt < 2; nt++){
            int wr = w * 32 + nt * 16 + r16;   /* weight row = output col (A-frag) */
            const u16* ap = wsbase + offW + (long)wr * 128 + q8;
            f32x4 acc; acc[0]=0.f; acc[1]=0.f; acc[2]=0.f; acc[3]=0.f;
#pragma unroll
            for (int kk = 0; kk < 4; kk++){
                bf16x8 av = *(const bf16x8*)(ap + kk * 32);
                bf16x8 bv = *(const bf16x8*)(bp + kk * 32);
                acc = __builtin_amdgcn_mfma_f32_16x16x32_bf16(av, bv, acc, 0, 0, 0);
            }
            /* lane owns node row r16, cols c0..c0+3 */
            int c0 = w * 32 + nt * 16 + q * 4;
            if (half == 0){
                f32x4 bc = ldf4(bias, c0, f32);
                float* Rf = (float*)(wsbase + offR);
                f32x4 rr; rr[0]=acc[0]+bc[0]; rr[1]=acc[1]+bc[1]; rr[2]=acc[2]+bc[2]; rr[3]=acc[3]+bc[3];
                *(f32x4*)(Rf + (long)(node0 + r16) * HH + c0) = rr;
            } else {
                uint2v u; u.x = f2b2(acc[0], acc[1]); u.y = f2b2(acc[2], acc[3]);
                *(uint2v*)(wsbase + offQ + (long)(node0 + r16) * HH + c0) = u;
            }
        }
    }
}

/* ---- swapped GEMM: D = W^T-tile (A) x message-rows (B); lane owns message
   row r16 (+16*mt) x 4 contiguous output cols (w*16 + q*4 ..) ---- */
__device__ __forceinline__ void mfma_WB(const u16* Mls, const bf16x8* W,
                                        f32x4 acc[3], int lane){
    const int r16 = lane & 15;
    const int q8  = (lane >> 4) * 8;
    const u16* bp = Mls + r16 * ST + q8;
#pragma unroll
    for (int kk = 0; kk < 4; kk++){
        bf16x8 b0 = *(const bf16x8*)(bp + kk * 32);
        bf16x8 b1 = *(const bf16x8*)(bp + 16 * ST + kk * 32);
        bf16x8 b2 = *(const bf16x8*)(bp + 32 * ST + kk * 32);
        acc[0] = __builtin_amdgcn_mfma_f32_16x16x32_bf16(W[kk], b0, acc[0], 0, 0, 0);
        acc[1] = __builtin_amdgcn_mfma_f32_16x16x32_bf16(W[kk], b1, acc[1], 0, 0, 0);
        acc[2] = __builtin_amdgcn_mfma_f32_16x16x32_bf16(W[kk], b2, acc[2], 0, 0, 0);
    }
}

__device__ __forceinline__ void zero_acc3(f32x4 acc[3]){
#pragma unroll
    for (int m = 0; m < 3; m++){ acc[m][0]=0.f; acc[m][1]=0.f; acc[m][2]=0.f; acc[m][3]=0.f; }
}

/* init acc with gathered-Q values from LDS (vector b64 reads; own cols only) */
__device__ __forceinline__ void init_accT(f32x4 acc[3], const u16* Qg, int lane, int w){
    const int r16 = lane & 15, q = lane >> 4;
    const int c0 = w * 16 + q * 4;
#pragma unroll
    for (int mt = 0; mt < 3; mt++){
        u16x4 v = *(const u16x4*)(Qg + (mt * 16 + r16) * ST + c0);
        acc[mt][0]=b2f(v[0]); acc[mt][1]=b2f(v[1]); acc[mt][2]=b2f(v[2]); acc[mt][3]=b2f(v[3]);
    }
}

/* +bias (per-col f32x4), optional gelu, pack, b64 LDS store (own cols only) */
__device__ __forceinline__ void store_T(f32x4 acc[3], u16* M, f32x4 bc4,
                                        int lane, int w, bool dogelu){
    const int r16 = lane & 15, q = lane >> 4;
    const int c0 = w * 16 + q * 4;
#pragma unroll
    for (int mt = 0; mt < 3; mt++){
        float v0 = acc[mt][0] + bc4[0], v1 = acc[mt][1] + bc4[1];
        float v2 = acc[mt][2] + bc4[2], v3 = acc[mt][3] + bc4[3];
        if (dogelu){ v0 = gelu_f(v0); v1 = gelu_f(v1); v2 = gelu_f(v2); v3 = gelu_f(v3); }
        uint2v u; u.x = f2b2(v0, v1); u.y = f2b2(v2, v3);
        *(uint2v*)(M + (mt * 16 + r16) * ST + c0) = u;
    }
}

/* ---- kernel 1: node message + LN1 -> hv1 (ws).
   GEMM3 is folded into a masked colsum + GEMV (linearity of the k-sum). ---- */
__global__ __launch_bounds__(512, 6) void node_kernel(
    const void* __restrict__ hV, const void* __restrict__ hE, const void* __restrict__ Eidx,
    const void* __restrict__ maskA,
    const void* __restrict__ b2, const void* __restrict__ b3,
    const void* __restrict__ ln1s, const void* __restrict__ ln1b,
    u16* __restrict__ wsbase)
{
    __shared__ alignas(16) u16 A[KN * ST];    /* h_E bf16 */
    __shared__ alignas(16) u16 Qg[KN * ST];   /* gathered Q1; M1 aliases (own-col writes) */
    __shared__ float smask[KN];
    __shared__ alignas(16) float sL[HH];      /* masked colsum of gelu(M1@W2+b2) */
    __shared__ alignas(16) float dh[HH];
    __shared__ float hv0f[HH];
    u16* M1 = Qg;

    const int f32 = ((const int*)wsbase)[0];
    const int i64 = ((const int*)wsbase)[1];
    const u16* ws = wsbase;
    const int t = threadIdx.x, lane = t & 63, w = t >> 6;
    const int bid = blockIdx.x;
    const int b = bid >> 11;
    const int r16 = lane & 15, q = lane >> 4, q8 = q * 8;
    const int wrow = w * 16 + r16;   /* weight row (A-frag lane index) */
    const int c0 = w * 16 + q * 4;   /* this lane's 4 output cols */

    /* prefetch W1-mid fragments (A-operand) */
    bf16x8 B1[4];
    {
        const u16* bp = ws + OFF_W1MT + (long)wrow * 128 + q8;
#pragma unroll
        for (int k = 0; k < 4; k++) B1[k] = *(const bf16x8*)(bp + k * 32);
    }

    for (int i = t; i < 768; i += 512){
        int row = i >> 4, ch = i & 15;
        stage8(A + row * ST + ch * 8, hE, ((long)bid * KN + row) * HH + ch * 8, f32);
    }
    for (int i = t; i < 768; i += 512){
        int row = i >> 4, ch = i & 15;
        int nb = ld_idx(Eidx, bid * KN + row, i64);
        *(uint4v*)(Qg + row * ST + ch * 8) =
            *(const uint4v*)(ws + OFF_Q1 + ((long)b * LL + nb) * HH + ch * 8);
    }
    if (t < HH) hv0f[t] = ldf(hV, (long)bid * HH + t, f32);
    if (t < KN) smask[t] = ldf(maskA, bid * KN + t, f32);

    bf16x8 B2[4];
    {
        const u16* bp = ws + OFF_W2T + (long)wrow * 128 + q8;
#pragma unroll
        for (int k = 0; k < 4; k++) B2[k] = *(const bf16x8*)(bp + k * 32);
    }
    /* per-col effective bias: b1 + hV_self @ W1[0:128] (precomputed f32) */
    const f32x4 bc1 = *(const f32x4*)((const float*)(wsbase + OFF_R1) + (long)bid * HH + c0);
    __syncthreads();

    f32x4 acc[3];
    init_accT(acc, Qg, lane, w);          /* reads own cols of Qg */
    __builtin_amdgcn_s_setprio(1);
    mfma_WB(A, B1, acc, lane);
    __builtin_amdgcn_s_setprio(0);
    store_T(acc, M1, bc1, lane, w, true); /* writes own cols of Qg-space: race-free */
    __syncthreads();

    zero_acc3(acc);
    __builtin_amdgcn_s_setprio(1);
    mfma_WB(M1, B2, acc, lane);
    __builtin_amdgcn_s_setprio(0);

    /* gelu in f32 + masked colsum over the 48 messages (k-sum commutes with W3) */
    float cnt;
    {
        f32x4 b2v = ldf4(b2, c0, f32);
        f32x4 s; s[0]=0.f; s[1]=0.f; s[2]=0.f; s[3]=0.f;
        float cm = smask[r16] + smask[16 + r16] + smask[32 + r16];
#pragma unroll
        for (int mt = 0; mt < 3; mt++){
            float mk = smask[mt * 16 + r16];
#pragma unroll
            for (int j = 0; j < 4; j++)
                s[j] += mk * gelu_f(acc[mt][j] + b2v[j]);
        }
#pragma unroll
        for (int off = 1; off <= 8; off <<= 1){
#pragma unroll
            for (int j = 0; j < 4; j++) s[j] += __shfl_xor(s[j], off);
            cm += __shfl_xor(cm, off);
        }
        cnt = cm;
        if (r16 == 0) *(f32x4*)&sL[c0] = s;
    }
    __syncthreads();

    /* GEMV: dh[n] = sL @ W3T[n] + cnt*b3[n]; 4 threads per n */
    {
        int n = t >> 2, p = t & 3;
        const u16* wr = ws + OFF_W3T + (long)n * 128 + p * 32;
        float a = 0.f;
#pragma unroll
        for (int cc = 0; cc < 8; cc++){
            u16x4 wv = *(const u16x4*)(wr + cc * 4);
            f32x4 sv = *(const f32x4*)&sL[p * 32 + cc * 4];
            a = fmaf(b2f(wv[0]), sv[0], a);
            a = fmaf(b2f(wv[1]), sv[1], a);
            a = fmaf(b2f(wv[2]), sv[2], a);
            a = fmaf(b2f(wv[3]), sv[3], a);
        }
        a += __shfl_xor(a, 1);
        a += __shfl_xor(a, 2);
        if (p == 0) dh[n] = a + cnt * ldf(b3, n, f32);
    }
    __syncthreads();

    /* LN1 (wave 0) -> hv1 bf16 */
    if (w == 0){
        float xa = hv0f[lane]      + dh[lane]      * (1.0f / 30.0f);
        float xb = hv0f[64 + lane] + dh[64 + lane] * (1.0f / 30.0f);
        float sum = xa + xb, sq = xa * xa + xb * xb;
#pragma unroll
        for (int off = 1; off < 64; off <<= 1){ sum += __shfl_xor(sum, off); sq += __shfl_xor(sq, off); }
        float mu = sum * (1.0f / 128.0f);
        float var = sq * (1.0f / 128.0f) - mu * mu;
        float rstd = rsqrtf(var + 1e-5f);
        wsbase[OFF_HV1 + (long)bid * HH + lane] =
            f2b((xa - mu) * rstd * ldf(ln1s, lane, f32) + ldf(ln1b, lane, f32));
        wsbase[OFF_HV1 + (long)bid * HH + 64 + lane] =
            f2b((xb - mu) * rstd * ldf(ln1s, 64 + lane, f32) + ldf(ln1b, 64 + lane, f32));
    }
}

/* ---- kernel 2: FFN (16 nodes/block, 512 thr) + LN2 + mask -> d_out h_V;
   fused precomp pass 2 (Q2/R2 for the edge kernel) ---- */
__global__ __launch_bounds__(512, 6) void ffn_kernel(
    const void* __restrict__ maskV,
    const void* __restrict__ bi, const void* __restrict__ bo,
    const void* __restrict__ b11,
    const void* __restrict__ ln2s, const void* __restrict__ ln2b,
    u16* __restrict__ wsbase, void* __restrict__ dout)
{
    __shared__ alignas(16) u16 X[16 * 136];
    __shared__ alignas(16) u16 Hid[16 * 520];
    __shared__ alignas(16) float V[16 * 132];

    const int f32 = ((const int*)wsbase)[0];
    const u16* ws = wsbase;
    const u16* hv1 = wsbase + OFF_HV1;
    const int t = threadIdx.x, lane = t & 63, w = t >> 6;
    const int node0 = blockIdx.x * 16;
    const int r16 = lane & 15, q = lane >> 4, q8 = q * 8;
    const int c0 = w * 16 + q * 4;

    if (t < 256){
        int row = t >> 4, ch = t & 15;
        *(uint4v*)(X + row * 136 + ch * 8) =
            *(const uint4v*)(hv1 + (long)(node0 + row) * HH + ch * 8);
    }
    __syncthreads();

    /* GEMM1 swapped: A = WiT rows (4 tiles: w*64 + nt*16), B = X rows */
    f32x4 acc[4];
#pragma unroll
    for (int nt = 0; nt < 4; nt++){ acc[nt][0]=0.f; acc[nt][1]=0.f; acc[nt][2]=0.f; acc[nt][3]=0.f; }
    {
        const u16* bp = X + r16 * 136 + q8;
#pragma unroll
        for (int kk = 0; kk < 4; kk++){
            bf16x8 bv = *(const bf16x8*)(bp + kk * 32);
#pragma unroll
            for (int nt = 0; nt < 4; nt++){
                const u16* ap = ws + OFF_WIT + (long)(w * 64 + nt * 16 + r16) * 128 + kk * 32 + q8;
                bf16x8 av = *(const bf16x8*)ap;
                acc[nt] = __builtin_amdgcn_mfma_f32_16x16x32_bf16(av, bv, acc[nt], 0, 0, 0);
            }
        }
    }
    /* lane owns node row r16 x 4 contiguous hid cols */
#pragma unroll
    for (int nt = 0; nt < 4; nt++){
        int hc0 = w * 64 + nt * 16 + q * 4;
        f32x4 bc = ldf4(bi, hc0, f32);
        float g0 = gelu_f(acc[nt][0] + bc[0]), g1 = gelu_f(acc[nt][1] + bc[1]);
        float g2 = gelu_f(acc[nt][2] + bc[2]), g3 = gelu_f(acc[nt][3] + bc[3]);
        uint2v u; u.x = f2b2(g0, g1); u.y = f2b2(g2, g3);
        *(uint2v*)(Hid + r16 * 520 + hc0) = u;
    }
    __syncthreads();

    /* GEMM2 swapped: A = WoT rows (w*16 + r16), B = Hid rows; K=512 */
    f32x4 acc2; acc2[0]=0.f; acc2[1]=0.f; acc2[2]=0.f; acc2[3]=0.f;
    {
        const u16* ap = ws + OFF_WOT + (long)(w * 16 + r16) * 512 + q8;
        const u16* bp = Hid + r16 * 520 + q8;
        __builtin_amdgcn_s_setprio(1);
#pragma unroll
        for (int kk = 0; kk < 16; kk++){
            bf16x8 av = *(const bf16x8*)(ap + kk * 32);
            bf16x8 bv = *(const bf16x8*)(bp + kk * 32);
            acc2 = __builtin_amdgcn_mfma_f32_16x16x32_bf16(av, bv, acc2, 0, 0, 0);
        }
        __builtin_amdgcn_s_setprio(0);
    }
    {   /* V = acc2 + bo + residual; lane: node row r16, cols c0.. */
        f32x4 bo4 = ldf4(bo, c0, f32);
        u16x4 xr = *(const u16x4*)(X + r16 * 136 + c0);
        f32x4 vv;
        vv[0] = acc2[0] + bo4[0] + b2f(xr[0]);
        vv[1] = acc2[1] + bo4[1] + b2f(xr[1]);
        vv[2] = acc2[2] + bo4[2] + b2f(xr[2]);
        vv[3] = acc2[3] + bo4[3] + b2f(xr[3]);
        *(f32x4*)&V[r16 * 132 + c0] = vv;
    }
    __syncthreads();

    /* LN2 + mask: 32 threads per row; store d_out and bf16 copy into X */
    {
        int row = t >> 5, p = t & 31;
        f32x4 v = *(const f32x4*)&V[row * 132 + p * 4];
        float sum = v[0] + v[1] + v[2] + v[3];
        float sq = v[0]*v[0] + v[1]*v[1] + v[2]*v[2] + v[3]*v[3];
#pragma unroll
        for (int off = 1; off < 32; off <<= 1){ sum += __shfl_xor(sum, off); sq += __shfl_xor(sq, off); }
        float mu = sum * (1.0f / 128.0f);
        float var = sq * (1.0f / 128.0f) - mu * mu;
        float rstd = rsqrtf(var + 1e-5f);
        float mv = ldf(maskV, node0 + row, f32);
        f32x4 s4 = ldf4(ln2s, p * 4, f32), bb4 = ldf4(ln2b, p * 4, f32);
        f32x4 y;
#pragma unroll
        for (int j = 0; j < 4; j++) y[j] = ((v[j] - mu) * rstd * s4[j] + bb4[j]) * mv;
        st4(dout, (long)(node0 + row) * HH + p * 4, y, f32);
        uint2v u; u.x = f2b2(y[0], y[1]); u.y = f2b2(y[2], y[3]);
        *(uint2v*)(X + row * 136 + p * 4) = u;
    }
    __syncthreads();

    /* fused precomp2: R2 = hv_new @ W11[0:128] + b11 (f32), Q2 = hv_new @ W11[256:384] (bf16) */
    {
        const u16* bp = X + r16 * 136 + q8;
        f32x4 aR, aQ;
        aR[0]=0.f; aR[1]=0.f; aR[2]=0.f; aR[3]=0.f;
        aQ[0]=0.f; aQ[1]=0.f; aQ[2]=0.f; aQ[3]=0.f;
#pragma unroll
        for (int kk = 0; kk < 4; kk++){
            bf16x8 bv = *(const bf16x8*)(bp + kk * 32);
            bf16x8 avR = *(const bf16x8*)(ws + OFF_W11ST + (long)(w * 16 + r16) * 128 + kk * 32 + q8);
            bf16x8 avQ = *(const bf16x8*)(ws + OFF_W11GT + (long)(w * 16 + r16) * 128 + kk * 32 + q8);
            aR = __builtin_amdgcn_mfma_f32_16x16x32_bf16(avR, bv, aR, 0, 0, 0);
            aQ = __builtin_amdgcn_mfma_f32_16x16x32_bf16(avQ, bv, aQ, 0, 0, 0);
        }
        f32x4 b11v = ldf4(b11, c0, f32);
        float* Rf = (float*)(wsbase + OFF_R2);
        f32x4 rr;
#pragma unroll
        for (int j = 0; j < 4; j++) rr[j] = aR[j] + b11v[j];
        *(f32x4*)(Rf + (long)(node0 + r16) * HH + c0) = rr;
        uint2v u; u.x = f2b2(aQ[0], aQ[1]); u.y = f2b2(aQ[2], aQ[3]);
        *(uint2v*)(wsbase + OFF_Q2 + (long)(node0 + r16) * HH + c0) = u;
    }
}

/* ---- kernel 3: edge update + LN3 (gathers precomputed Q2 from ws) ---- */
__global__ __launch_bounds__(512, 6) void edge_kernel(
    const void* __restrict__ hE, const void* __restrict__ Eidx,
    const void* __restrict__ b12, const void* __restrict__ b13,
    const void* __restrict__ ln3s, const void* __restrict__ ln3b,
    u16* __restrict__ wsbase, void* __restrict__ dout)
{
    __shared__ alignas(16) u16 A[KN * ST];    /* h_E bf16; M2 aliases */
    __shared__ alignas(16) u16 Qg[KN * ST];   /* gathered Q2; M1 aliases (own-col writes) */
    __shared__ float rowsum[KN];
    __shared__ float rowsq[KN];
    u16* M1 = Qg;
    u16* M2 = A;

    const int f32 = ((const int*)wsbase)[0];
    const int i64 = ((const int*)wsbase)[1];
    const u16* ws = wsbase;
    const int t = threadIdx.x, lane = t & 63, w = t >> 6;
    const int bid = blockIdx.x;
    const int b = bid >> 11;
    const int r16 = lane & 15, q = lane >> 4, q8 = q * 8;
    const int wrow = w * 16 + r16;
    const int c0 = w * 16 + q * 4;

    bf16x8 B1[4];
    {
        const u16* bp = ws + OFF_W11MT + (long)wrow * 128 + q8;
#pragma unroll
        for (int k = 0; k < 4; k++) B1[k] = *(const bf16x8*)(bp + k * 32);
    }

    for (int i = t; i < 768; i += 512){
        int row = i >> 4, ch = i & 15;
        stage8(A + row * ST + ch * 8, hE, ((long)bid * KN + row) * HH + ch * 8, f32);
    }
    for (int i = t; i < 768; i += 512){
        int row = i >> 4, ch = i & 15;
        int nb = ld_idx(Eidx, bid * KN + row, i64);
        *(uint4v*)(Qg + row * ST + ch * 8) =
            *(const uint4v*)(ws + OFF_Q2 + ((long)b * LL + nb) * HH + ch * 8);
    }
    if (t < KN){ rowsum[t] = 0.f; rowsq[t] = 0.f; }

    bf16x8 B2[4];
    {
        const u16* bp = ws + OFF_W12T + (long)wrow * 128 + q8;
#pragma unroll
        for (int k = 0; k < 4; k++) B2[k] = *(const bf16x8*)(bp + k * 32);
    }
    const f32x4 bc1 = *(const f32x4*)((const float*)(wsbase + OFF_R2) + (long)bid * HH + c0);
    __syncthreads();

    f32x4 acc[3];
    init_accT(acc, Qg, lane, w);          /* reads own cols of Qg */
    __builtin_amdgcn_s_setprio(1);
    mfma_WB(A, B1, acc, lane);
    __builtin_amdgcn_s_setprio(0);
    store_T(acc, M1, bc1, lane, w, true); /* writes own cols of Qg-space: race-free */

    bf16x8 B3[4];
    {
        const u16* bp = ws + OFF_W13T + (long)wrow * 128 + q8;
#pragma unroll
        for (int k = 0; k < 4; k++) B3[k] = *(const bf16x8*)(bp + k * 32);
    }
    __syncthreads();

    zero_acc3(acc);
    __builtin_amdgcn_s_setprio(1);
    mfma_WB(M1, B2, acc, lane);
    __builtin_amdgcn_s_setprio(0);
    store_T(acc, M2, ldf4(b12, c0, f32), lane, w, true);   /* A dead after barrier */
    __syncthreads();

    zero_acc3(acc);
    __builtin_amdgcn_s_setprio(1);
    mfma_WB(M2, B3, acc, lane);
    __builtin_amdgcn_s_setprio(0);

    /* epilogue: lane owns rows {r16, 16+r16, 32+r16} x cols c0..c0+3 */
    f32x4 vals[3];
    {
        f32x4 b13v = ldf4(b13, c0, f32);
#pragma unroll
        for (int mt = 0; mt < 3; mt++){
            int r = mt * 16 + r16;
            f32x4 res = ldf4(hE, ((long)bid * KN + r) * HH + c0, f32);  /* residual (L2-hit) */
#pragma unroll
            for (int j = 0; j < 4; j++) vals[mt][j] = acc[mt][j] + b13v[j] + res[j];
        }
    }
    /* LN3 stats: per-lane 4-col partials, reduce over q (xor 16,32), cross-wave atomics */
    {
        float s[3], ss[3];
#pragma unroll
        for (int mt = 0; mt < 3; mt++){
            s[mt]  = vals[mt][0] + vals[mt][1] + vals[mt][2] + vals[mt][3];
            ss[mt] = vals[mt][0]*vals[mt][0] + vals[mt][1]*vals[mt][1]
                   + vals[mt][2]*vals[mt][2] + vals[mt][3]*vals[mt][3];
            s[mt]  += __shfl_xor(s[mt], 16);  s[mt]  += __shfl_xor(s[mt], 32);
            ss[mt] += __shfl_xor(ss[mt], 16); ss[mt] += __shfl_xor(ss[mt], 32);
        }
        if (lane < 16){
#pragma unroll
            for (int mt = 0; mt < 3; mt++){
                atomicAdd(&rowsum[mt * 16 + lane], s[mt]);
                atomicAdd(&rowsq[mt * 16 + lane], ss[mt]);
            }
        }
    }
    __syncthreads();
    if (t < KN){
        float mu = rowsum[t] * (1.0f / 128.0f);
        float var = rowsq[t] * (1.0f / 128.0f) - mu * mu;
        rowsum[t] = mu;
        rowsq[t] = rsqrtf(var + 1e-5f);
    }
    __syncthreads();

    {
        long ebase = (long)BB * LL * HH;
        f32x4 g4 = ldf4(ln3s, c0, f32), be4 = ldf4(ln3b, c0, f32);
#pragma unroll
        for (int mt = 0; mt < 3; mt++){
            int r = mt * 16 + r16;
            float mu = rowsum[r], rs = rowsq[r];
            f32x4 y;
#pragma unroll
            for (int j = 0; j < 4; j++) y[j] = (vals[mt][j] - mu) * rs * g4[j] + be4[j];
            st4(dout, ebase + ((long)bid * KN + r) * HH + c0, y, f32);
        }
    }
}

extern "C" void kernel_launch(void* const* d_in, const int* in_sizes, int n_in,
                              void* d_out, int out_size, void* d_ws, size_t ws_size,
                              hipStream_t stream) {
    const void* hV    = d_in[0];
    const void* hE    = d_in[1];
    const void* Eidx  = d_in[2];
    const void* maskV = d_in[3];
    const void* maskA = d_in[4];
    const void* W1  = d_in[5];  const void* b1  = d_in[6];
    const void* W2  = d_in[7];  const void* b2  = d_in[8];
    const void* W3  = d_in[9];  const void* b3  = d_in[10];
    const void* W11 = d_in[11]; const void* b11 = d_in[12];
    const void* W12 = d_in[13]; const void* b12 = d_in[14];
    const void* W13 = d_in[15]; const void* b13 = d_in[16];
    const void* Wi  = d_in[17]; const void* bi  = d_in[18];
    const void* Wo  = d_in[19]; const void* bo  = d_in[20];
    const void* ln1s = d_in[21]; const void* ln1b = d_in[22];
    const void* ln2s = d_in[23]; const void* ln2b = d_in[24];
    const void* ln3s = d_in[25]; const void* ln3b = d_in[26];

    u16* ws = (u16*)d_ws;

    prep_kernel<<<(PREP_N + 255) / 256, 256, 0, stream>>>(W1, W2, W3, W11, W12, W13, Wi, Wo,
                                                          ln1s, maskV, Eidx, ws);
    precomp_kernel<<<NBLK / 16, 256, 0, stream>>>(hV, b1, ws,
                                                  (long)OFF_W1ST, (long)OFF_W1GT,
                                                  (long)OFF_Q1, (long)OFF_R1);
    node_kernel<<<NBLK, 512, 0, stream>>>(hV, hE, Eidx, maskA,
                                          b2, b3, ln1s, ln1b, ws);
    ffn_kernel<<<NBLK / 16, 512, 0, stream>>>(maskV, bi, bo, b11, ln2s, ln2b, ws, d_out);
    edge_kernel<<<NBLK, 512, 0, stream>>>(hE, Eidx, b12, b13,
                                          ln3s, ln3b, ws, d_out);
}